// Round 9
// baseline (9931.363 us; speedup 1.0000x reference)
//
#include <hip/hip_runtime.h>
#include <hip/hip_bf16.h>
#include <math.h>

constexpr int NN  = 100000;   // nodes
constexpr int EE  = 3200000;  // edges
constexpr int HID = 128;
constexpr int NG  = 512;      // 4*HID
constexpr int NOUT = 64;
constexpr int HOPS = 10;
constexpr int SCAN_BLK = 1024;
constexpr int NBLK_SCAN = (NN + SCAN_BLK - 1) / SCAN_BLK;   // 98
constexpr int NB = (NN + 255) / 256;                        // 391 row-buckets (256 rows each)
constexpr int PA_BATCH = 4096;                              // edges per pass-A block
constexpr int PA_GRID = (EE + PA_BATCH - 1) / PA_BATCH;     // 782
constexpr int GRP = 16;                                     // rows per spmm group
constexpr int NGRP = NN / GRP;                              // 6250
constexpr int NKEY = 13 * GRP;                              // (slice, row_local) keys = 208

typedef __attribute__((ext_vector_type(8))) short short8;
typedef __attribute__((ext_vector_type(4))) float f32x4;
typedef unsigned long long ull;

__device__ __forceinline__ ushort f2bf(float f) {
    uint u = __builtin_bit_cast(uint, f);
    u += 0x7fff + ((u >> 16) & 1);          // RNE
    return (ushort)(u >> 16);
}
__device__ __forceinline__ float bflo(uint u) { return __builtin_bit_cast(float, u << 16); }
__device__ __forceinline__ float bfhi(uint u) { return __builtin_bit_cast(float, u & 0xffff0000u); }

__device__ __forceinline__ float sigf(float v) { return 1.0f / (1.0f + __expf(-v)); }
__device__ __forceinline__ float tanh_fast(float x) {
    float t = __expf(-2.0f * fabsf(x));
    float r = (1.0f - t) / (1.0f + t);
    return copysignf(r, x);
}

__device__ __forceinline__ short8 load_frag(const ushort* p) {
    return *reinterpret_cast<const short8*>(p);
}
__device__ __forceinline__ f32x4 mfma16(short8 a, short8 b, f32x4 c) {
    return __builtin_amdgcn_mfma_f32_16x16x32_bf16(a, b, c, 0, 0, 0);
}

// ---------------------------------------------------------------------------
// fp32 -> bf16 conversion (vectorized), n4 = n/4
// ---------------------------------------------------------------------------
__global__ __launch_bounds__(256) void convert_bf16_kernel(
    const float* __restrict__ src, ushort* __restrict__ dst, int n4)
{
    int i = blockIdx.x * 256 + threadIdx.x;
    if (i < n4) {
        float4 v = reinterpret_cast<const float4*>(src)[i];
        ushort4 o;
        o.x = f2bf(v.x); o.y = f2bf(v.y); o.z = f2bf(v.z); o.w = f2bf(v.w);
        reinterpret_cast<ushort4*>(dst)[i] = o;
    }
}

__global__ __launch_bounds__(256) void bsum_kernel(
    const float* __restrict__ bih, const float* __restrict__ bhh, float* __restrict__ bsum)
{
    int i = blockIdx.x * 256 + threadIdx.x;
    if (i < NG) bsum[i] = bih[i] + bhh[i];
}

// ---------------------------------------------------------------------------
// CSR build: histogram -> 3-stage scan -> bucketed 2-pass scatter -> group sort
// ---------------------------------------------------------------------------
__global__ __launch_bounds__(256) void hist_kernel(const int* __restrict__ erow,
                                                   int* __restrict__ deg)
{
    int e = blockIdx.x * 256 + threadIdx.x;
    atomicAdd(&deg[erow[e]], 1);
}

__global__ __launch_bounds__(SCAN_BLK) void scan1_kernel(const int* __restrict__ deg,
                                                         int* __restrict__ bsums)
{
    __shared__ int tmp[SCAN_BLK];
    int t = threadIdx.x;
    int i = blockIdx.x * SCAN_BLK + t;
    tmp[t] = (i < NN) ? deg[i] : 0;
    __syncthreads();
    for (int off = SCAN_BLK / 2; off > 0; off >>= 1) {
        if (t < off) tmp[t] += tmp[t + off];
        __syncthreads();
    }
    if (t == 0) bsums[blockIdx.x] = tmp[0];
}

__global__ __launch_bounds__(128) void scan2_kernel(int* __restrict__ bsums)
{
    __shared__ int tmp[128];
    int t = threadIdx.x;
    tmp[t] = (t < NBLK_SCAN) ? bsums[t] : 0;
    __syncthreads();
    for (int off = 1; off < 128; off <<= 1) {
        int add = (t >= off) ? tmp[t - off] : 0;
        __syncthreads();
        tmp[t] += add;
        __syncthreads();
    }
    if (t < NBLK_SCAN) bsums[t] = (t == 0) ? 0 : tmp[t - 1];
}

__global__ __launch_bounds__(SCAN_BLK) void scan3_kernel(const int* __restrict__ deg,
                                                         const int* __restrict__ bsums,
                                                         int* __restrict__ rp,
                                                         int* __restrict__ cur)
{
    __shared__ int tmp[SCAN_BLK];
    int t = threadIdx.x;
    int i = blockIdx.x * SCAN_BLK + t;
    int v = (i < NN) ? deg[i] : 0;
    tmp[t] = v;
    __syncthreads();
    for (int off = 1; off < SCAN_BLK; off <<= 1) {
        int add = (t >= off) ? tmp[t - off] : 0;
        __syncthreads();
        tmp[t] += add;
        __syncthreads();
    }
    int incl = tmp[t] + bsums[blockIdx.x];
    if (i < NN) {
        rp[i + 1] = incl;
        cur[i] = incl - v;
    }
    if (i == 0) rp[0] = 0;
}

__global__ __launch_bounds__(512) void binit_kernel(const int* __restrict__ rp,
                                                    int* __restrict__ bcur)
{
    int b = threadIdx.x;
    if (b < NB) bcur[b] = rp[b << 8];
}

// pass A: partition edges into 391 row-buckets (block-local LDS binning)
__global__ __launch_bounds__(256) void passA_kernel(
    const int* __restrict__ erow, const int* __restrict__ ecol,
    const float* __restrict__ eval, int* __restrict__ bcur,
    int* __restrict__ trow, int2* __restrict__ tcv)
{
    __shared__ int  lhist[512];
    __shared__ int  sa[512];
    __shared__ int  sb[512];
    __shared__ int  gbase[512];
    __shared__ int  srow[PA_BATCH];
    __shared__ int2 scv[PA_BATCH];

    const int t = threadIdx.x;
    const int base = blockIdx.x * PA_BATCH;
    const int nb = min(PA_BATCH, EE - base);

    lhist[t] = 0; lhist[t + 256] = 0;
    __syncthreads();

    int er[16], ec[16], pk[16];
    float ev[16];
#pragma unroll
    for (int k = 0; k < 16; ++k) {
        int idx = k * 256 + t;
        if (idx < nb) {
            int e = base + idx;
            int r = erow[e];
            er[k] = r; ec[k] = ecol[e]; ev[k] = eval[e];
            int b = r >> 8;
            int pos = atomicAdd(&lhist[b], 1);
            pk[k] = b | (pos << 9);
        } else pk[k] = -1;
    }
    __syncthreads();

    sa[t] = lhist[t]; sa[t + 256] = lhist[t + 256];
    __syncthreads();
    int* src = sa; int* dst = sb;
    for (int off = 1; off < 512; off <<= 1) {
        dst[t] = src[t] + ((t >= off) ? src[t - off] : 0);
        int i2 = t + 256;
        dst[i2] = src[i2] + src[i2 - off];
        __syncthreads();
        int* tp = src; src = dst; dst = tp;
    }
    int* incl = src;

    for (int b = t; b < NB; b += 256) {
        int cnt = lhist[b];
        gbase[b] = cnt ? atomicAdd(&bcur[b], cnt) : 0;
    }
    __syncthreads();

#pragma unroll
    for (int k = 0; k < 16; ++k) {
        if (pk[k] >= 0) {
            int b = pk[k] & 511;
            int pos = pk[k] >> 9;
            int lofs = b ? incl[b - 1] : 0;
            int s = lofs + pos;
            srow[s] = er[k];
            scv[s] = int2{ec[k], __builtin_bit_cast(int, ev[k])};
        }
    }
    __syncthreads();

    for (int s = t; s < nb; s += 256) {
        int rr = srow[s];
        int b = rr >> 8;
        int lofs = b ? incl[b - 1] : 0;
        int g = gbase[b] + (s - lofs);
        trow[g] = rr;
        tcv[g] = scv[s];
    }
}

__global__ __launch_bounds__(256) void passB_kernel(
    const int* __restrict__ trow, const int2* __restrict__ tcv,
    int* __restrict__ cur, int2* __restrict__ epack)
{
    int e = blockIdx.x * 256 + threadIdx.x;
    int r = trow[e];
    int2 cv = tcv[e];
    int p = atomicAdd(&cur[r], 1);
    epack[p] = cv;
}

// ---------------------------------------------------------------------------
// groupsort: per 16-row group, counting-sort its CSR range by key
// (col_slice, row_local); embed row_local in col bits 17..20. In-place.
// Gives spmm waves a phase-aligned monotone sweep over h's 2MB slices.
// ---------------------------------------------------------------------------
__global__ __launch_bounds__(256) void groupsort_kernel(
    const int* __restrict__ rp, int2* __restrict__ epack)
{
    __shared__ int2 sedge[1024];
    __shared__ int  rank[1024];
    __shared__ int  cnt[NKEY];
    __shared__ int  koff[NKEY];
    __shared__ int  scan[256];
    __shared__ int  srp[GRP + 1];

    const int g = blockIdx.x;
    const int t = threadIdx.x;
    if (t <= GRP) srp[t] = rp[g * GRP + t];
    if (t < NKEY) cnt[t] = 0;
    __syncthreads();
    const int beg = srp[0], end = srp[GRP];
    const int n = end - beg;

    if (n > 1024) {
        // fallback: embed row_local only (unsorted — correct, just slower spmm)
        for (int i = t; i < n; i += 256) {
            int gi = beg + i;
            int2 cv = epack[gi];
            int rl = 0;
#pragma unroll
            for (int k = 1; k < GRP; ++k) rl += (gi >= srp[k]) ? 1 : 0;
            cv.x |= (rl << 17);
            epack[gi] = cv;
        }
        return;
    }

    // load + compute key + rank
    for (int i = t; i < n; i += 256) {
        int gi = beg + i;
        int2 cv = epack[gi];
        int rl = 0;
#pragma unroll
        for (int k = 1; k < GRP; ++k) rl += (gi >= srp[k]) ? 1 : 0;
        cv.x |= (rl << 17);
        sedge[i] = cv;
        int key = ((cv.x & 0x1FFFF) >> 13) * GRP + rl;
        rank[i] = atomicAdd(&cnt[key], 1);
    }
    __syncthreads();

    // exclusive scan of cnt -> koff
    scan[t] = (t < NKEY) ? cnt[t] : 0;
    __syncthreads();
    for (int off = 1; off < 256; off <<= 1) {
        int add = (t >= off) ? scan[t - off] : 0;
        __syncthreads();
        scan[t] += add;
        __syncthreads();
    }
    if (t < NKEY) koff[t] = (t == 0) ? 0 : scan[t - 1];
    __syncthreads();

    // scatter back (in-place safe: fully staged in LDS)
    for (int i = t; i < n; i += 256) {
        int2 cv = sedge[i];
        int key = ((cv.x & 0x1FFFF) >> 13) * GRP + (cv.x >> 17);
        epack[beg + koff[key] + rank[i]] = cv;
    }
}

// ---------------------------------------------------------------------------
// Fused LSTM cell, wave-specialized gates, two-pass K-loop (x-pass, h-pass).
// Block = 32 rows, 4 waves, 3 waves/SIMD.
// ---------------------------------------------------------------------------
template<bool FIRST>
__global__ __launch_bounds__(256, 3) void cell_kernel(
    const ushort* __restrict__ xb, const ushort* __restrict__ hb,
    const ushort* __restrict__ Wib, const ushort* __restrict__ Whb,
    const float* __restrict__ bsum, float* __restrict__ cperm,
    ushort* __restrict__ hout)
{
    __shared__ __align__(16) ushort lds_h[32 * 136];

    const int t  = threadIdx.x;
    const int l  = t & 63;
    const int w  = t >> 6;
    const int lr = l & 15;
    const int lk = l >> 4;
    const int row0 = blockIdx.x * 32;

    f32x4 acc[8][2];
#pragma unroll
    for (int nI = 0; nI < 8; ++nI) {
        float b = bsum[(4 * nI + w) * 16 + lr];
        acc[nI][0] = f32x4{b, b, b, b};
        acc[nI][1] = f32x4{b, b, b, b};
    }

    // ---- pass 1: x @ W_ih^T ----
    {
        short8 ax[2][4];
#pragma unroll
        for (int rf = 0; rf < 2; ++rf) {
            const size_t arow = (size_t)(row0 + rf * 16 + lr) * HID + lk * 8;
#pragma unroll
            for (int ks = 0; ks < 4; ++ks)
                ax[rf][ks] = load_frag(xb + arow + ks * 32);
        }
#pragma unroll
        for (int nI = 0; nI < 8; ++nI) {
            const int n = 4 * nI + w;
            const ushort* wip = Wib + (size_t)(n * 16 + lr) * HID + lk * 8;
            short8 bi[4];
#pragma unroll
            for (int ks = 0; ks < 4; ++ks) bi[ks] = load_frag(wip + ks * 32);
#pragma unroll
            for (int rf = 0; rf < 2; ++rf)
#pragma unroll
                for (int ks = 0; ks < 4; ++ks)
                    acc[nI][rf] = mfma16(ax[rf][ks], bi[ks], acc[nI][rf]);
        }
    }
    __builtin_amdgcn_sched_barrier(0);
    // ---- pass 2: h @ W_hh^T ----
    if (!FIRST) {
        short8 ah[2][4];
#pragma unroll
        for (int rf = 0; rf < 2; ++rf) {
            const size_t arow = (size_t)(row0 + rf * 16 + lr) * HID + lk * 8;
#pragma unroll
            for (int ks = 0; ks < 4; ++ks)
                ah[rf][ks] = load_frag(hb + arow + ks * 32);
        }
#pragma unroll
        for (int nI = 0; nI < 8; ++nI) {
            const int n = 4 * nI + w;
            const ushort* whp = Whb + (size_t)(n * 16 + lr) * HID + lk * 8;
            short8 bh[4];
#pragma unroll
            for (int ks = 0; ks < 4; ++ks) bh[ks] = load_frag(whp + ks * 32);
#pragma unroll
            for (int rf = 0; rf < 2; ++rf)
#pragma unroll
                for (int ks = 0; ks < 4; ++ks)
                    acc[nI][rf] = mfma16(ah[rf][ks], bh[ks], acc[nI][rf]);
        }
    }

    // epilogue: LSTM elementwise; c in permuted layout, h via LDS transpose
#pragma unroll
    for (int nj = 0; nj < 2; ++nj) {
        const int col = (w + 4 * nj) * 16 + lr;
#pragma unroll
        for (int rf = 0; rf < 2; ++rf) {
            f32x4 iv = acc[nj][rf];
            f32x4 fv = acc[nj + 2][rf];
            f32x4 gv = acc[nj + 4][rf];
            f32x4 ov = acc[nj + 6][rf];
            const size_t cidx = ((((size_t)blockIdx.x * 4 + w) * 2 + nj) * 2 + rf) * 64 + l;
            f32x4 cold;
            if (FIRST) cold = f32x4{0.f, 0.f, 0.f, 0.f};
            else       cold = reinterpret_cast<const f32x4*>(cperm)[cidx];
            f32x4 cn, hn;
#pragma unroll
            for (int jj = 0; jj < 4; ++jj) {
                float c2 = sigf(fv[jj]) * cold[jj] + sigf(iv[jj]) * tanh_fast(gv[jj]);
                cn[jj] = c2;
                hn[jj] = sigf(ov[jj]) * tanh_fast(c2);
            }
            reinterpret_cast<f32x4*>(cperm)[cidx] = cn;
            const int rbase = rf * 16 + lk * 4;
#pragma unroll
            for (int jj = 0; jj < 4; ++jj)
                lds_h[(rbase + jj) * 136 + col] = f2bf(hn[jj]);
        }
    }
    __syncthreads();
    {
        const ushort* lsrc = &lds_h[(t >> 3) * 136 + (t & 7) * 16];
        short8 v0 = *reinterpret_cast<const short8*>(lsrc);
        short8 v1 = *reinterpret_cast<const short8*>(lsrc + 8);
        ushort* gdst = hout + (size_t)row0 * HID + t * 16;
        *reinterpret_cast<short8*>(gdst) = v0;
        *reinterpret_cast<short8*>(gdst + 8) = v1;
    }
}

// ---------------------------------------------------------------------------
// SpMM v2: one wave per 16-row group; LDS accumulator [16][128] fp32 per wave
// (wave-private, no barriers). Edge stream is (slice,row_local)-sorted, so all
// waves sweep h's 2MB slices in phase -> per-XCD L2 holds the active slice.
// Register-pair accumulation over same-row runs, LDS atomicAdd flush on change.
// ---------------------------------------------------------------------------
__global__ __launch_bounds__(256) void spmm_kernel(
    const int* __restrict__ rp, const int2* __restrict__ epack,
    const ushort* __restrict__ hin, ushort* __restrict__ hout)
{
    __shared__ float lds_acc[4 * GRP * HID];   // 32 KB

    const int w = threadIdx.x >> 6;
    const int l = threadIdx.x & 63;
    const int g = blockIdx.x * 4 + w;
    if (g >= NGRP) return;
    float* wacc = lds_acc + w * (GRP * HID);

    // zero wave-private accumulator (2048 floats / 64 lanes = 32 each)
#pragma unroll
    for (int k = 0; k < 32; ++k) wacc[k * 64 + l] = 0.f;

    const int beg = rp[g * GRP], end = rp[g * GRP + GRP];
    const ull* eq = reinterpret_cast<const ull*>(epack);

    int cur = -1;
    float a0 = 0.f, a1 = 0.f;
    const int fidx = 2 * l;

    int e = beg;
    for (; e + 4 <= end; e += 4) {
        ull u0 = __builtin_nontemporal_load(eq + e);
        ull u1 = __builtin_nontemporal_load(eq + e + 1);
        ull u2 = __builtin_nontemporal_load(eq + e + 2);
        ull u3 = __builtin_nontemporal_load(eq + e + 3);
        uint x0 = (uint)u0, x1 = (uint)u1, x2 = (uint)u2, x3 = (uint)u3;
        uint g0 = *reinterpret_cast<const uint*>(hin + (size_t)(x0 & 0x1FFFF) * HID + fidx);
        uint g1 = *reinterpret_cast<const uint*>(hin + (size_t)(x1 & 0x1FFFF) * HID + fidx);
        uint g2 = *reinterpret_cast<const uint*>(hin + (size_t)(x2 & 0x1FFFF) * HID + fidx);
        uint g3 = *reinterpret_cast<const uint*>(hin + (size_t)(x3 & 0x1FFFF) * HID + fidx);
#define PROC(xx, uu, gg)                                                        \
        {                                                                       \
            int rl = (int)((xx) >> 17);                                         \
            float vv = __builtin_bit_cast(float, (uint)((uu) >> 32));           \
            if (rl != cur) {                                                    \
                if (cur >= 0) {                                                 \
                    atomicAdd(&wacc[cur * HID + fidx], a0);                     \
                    atomicAdd(&wacc[cur * HID + fidx + 1], a1);                 \
                }                                                               \
                cur = rl; a0 = 0.f; a1 = 0.f;                                   \
            }                                                                   \
            a0 += vv * bflo(gg); a1 += vv * bfhi(gg);                           \
        }
        PROC(x0, u0, g0)
        PROC(x1, u1, g1)
        PROC(x2, u2, g2)
        PROC(x3, u3, g3)
    }
    for (; e < end; ++e) {
        ull u0 = __builtin_nontemporal_load(eq + e);
        uint x0 = (uint)u0;
        uint g0 = *reinterpret_cast<const uint*>(hin + (size_t)(x0 & 0x1FFFF) * HID + fidx);
        PROC(x0, u0, g0)
    }
#undef PROC
    if (cur >= 0) {
        atomicAdd(&wacc[cur * HID + fidx], a0);
        atomicAdd(&wacc[cur * HID + fidx + 1], a1);
    }

    // writeback: 16 rows, bf16-packed, coalesced 256B per row per wave
#pragma unroll
    for (int rl = 0; rl < GRP; ++rl) {
        float f0 = wacc[rl * HID + fidx];
        float f1 = wacc[rl * HID + fidx + 1];
        uint o = ((uint)f2bf(f1) << 16) | (uint)f2bf(f0);
        *reinterpret_cast<uint*>(hout + (size_t)(g * GRP + rl) * HID + fidx) = o;
    }
}

// ---------------------------------------------------------------------------
// final: out = relu(h) @ fc_w^T + fc_b  (MFMA)
// ---------------------------------------------------------------------------
__global__ __launch_bounds__(256) void final_mfma_kernel(
    const ushort* __restrict__ hb, const ushort* __restrict__ fcwb,
    const float* __restrict__ fcb, float* __restrict__ out)
{
    const int t = threadIdx.x;
    const int l = t & 63;
    const int w = t >> 6;
    const int lr = l & 15;
    const int lk = l >> 4;
    const int row0 = blockIdx.x * 64 + w * 16;

    f32x4 acc[4];
#pragma unroll
    for (int n = 0; n < 4; ++n) {
        float b = fcb[n * 16 + lr];
        acc[n] = f32x4{b, b, b, b};
    }

    const short8 z8 = {0, 0, 0, 0, 0, 0, 0, 0};
    const int arow = row0 + lr;
    const bool aok = arow < NN;
    short8 a[4];
#pragma unroll
    for (int ks = 0; ks < 4; ++ks) {
        short8 v = aok ? load_frag(hb + (size_t)arow * HID + ks * 32 + lk * 8) : z8;
#pragma unroll
        for (int i = 0; i < 8; ++i) {
            ushort u = (ushort)v[i];
            if (u & 0x8000) v[i] = 0;   // relu in bf16
        }
        a[ks] = v;
    }

#pragma unroll
    for (int n = 0; n < 4; ++n) {
        const ushort* wp = fcwb + (size_t)(n * 16 + lr) * HID + lk * 8;
#pragma unroll
        for (int ks = 0; ks < 4; ++ks)
            acc[n] = mfma16(a[ks], load_frag(wp + ks * 32), acc[n]);
    }

#pragma unroll
    for (int n = 0; n < 4; ++n) {
#pragma unroll
        for (int j = 0; j < 4; ++j) {
            int row = row0 + lk * 4 + j;
            if (row < NN) out[(size_t)row * NOUT + n * 16 + lr] = acc[n][j];
        }
    }
}

// ---------------------------------------------------------------------------
extern "C" void kernel_launch(void* const* d_in, const int* in_sizes, int n_in,
                              void* d_out, int out_size, void* d_ws, size_t ws_size,
                              hipStream_t stream)
{
    const float* x    = (const float*)d_in[0];
    const int*   erow = (const int*)d_in[1];
    const int*   ecol = (const int*)d_in[2];
    const float* eval = (const float*)d_in[3];
    const float* Wih  = (const float*)d_in[4];
    const float* Whh  = (const float*)d_in[5];
    const float* bih  = (const float*)d_in[6];
    const float* bhh  = (const float*)d_in[7];
    const float* fcw  = (const float*)d_in[8];
    const float* fcb  = (const float*)d_in[9];
    float* out = (float*)d_out;

    char* ws = (char*)d_ws;
    size_t off = 0;
    auto alloc = [&](size_t bytes) -> void* {
        void* p = ws + off;
        off = (off + bytes + 255) & ~(size_t)255;
        return p;
    };
    ushort* hb_a  = (ushort*)alloc((size_t)NN * HID * 2);
    ushort* hb_b  = (ushort*)alloc((size_t)NN * HID * 2);
    float*  cperm = (float*)alloc((size_t)NN * HID * 4);
    ushort* xb    = (ushort*)alloc((size_t)NN * HID * 2);
    ushort* Wib   = (ushort*)alloc((size_t)NG * HID * 2);
    ushort* Whb   = (ushort*)alloc((size_t)NG * HID * 2);
    ushort* fcwb  = (ushort*)alloc((size_t)NOUT * HID * 2);
    float*  bsum  = (float*)alloc((size_t)NG * 4);
    int*    rp    = (int*)alloc((size_t)(NN + 1) * 4);
    int*    deg   = (int*)alloc((size_t)NN * 4);
    int*    cur   = (int*)alloc((size_t)NN * 4);
    int*    bsums = (int*)alloc((size_t)NBLK_SCAN * 4);
    int*    bcur  = (int*)alloc((size_t)NB * 4);
    int2*   epack = (int2*)alloc((size_t)EE * 8);
    (void)ws_size;

    // temp bucket-grouped edge arrays alias cperm (written only after CSR build)
    int2* tcv  = (int2*)cperm;                               // 25.6 MB
    int*  trow = (int*)((char*)cperm + (size_t)EE * 8);      // 12.8 MB (total 38.4 <= 51.2)

    // conversions to bf16
    convert_bf16_kernel<<<(NN * HID / 4 + 255) / 256, 256, 0, stream>>>(x, xb, NN * HID / 4);
    convert_bf16_kernel<<<(NG * HID / 4 + 255) / 256, 256, 0, stream>>>(Wih, Wib, NG * HID / 4);
    convert_bf16_kernel<<<(NG * HID / 4 + 255) / 256, 256, 0, stream>>>(Whh, Whb, NG * HID / 4);
    convert_bf16_kernel<<<(NOUT * HID / 4 + 255) / 256, 256, 0, stream>>>(fcw, fcwb, NOUT * HID / 4);
    bsum_kernel<<<2, 256, 0, stream>>>(bih, bhh, bsum);

    // CSR build
    hipMemsetAsync(deg, 0, (size_t)NN * 4, stream);
    hist_kernel<<<EE / 256, 256, 0, stream>>>(erow, deg);
    scan1_kernel<<<NBLK_SCAN, SCAN_BLK, 0, stream>>>(deg, bsums);
    scan2_kernel<<<1, 128, 0, stream>>>(bsums);
    scan3_kernel<<<NBLK_SCAN, SCAN_BLK, 0, stream>>>(deg, bsums, rp, cur);
    binit_kernel<<<1, 512, 0, stream>>>(rp, bcur);
    passA_kernel<<<PA_GRID, 256, 0, stream>>>(erow, ecol, eval, bcur, trow, tcv);
    passB_kernel<<<EE / 256, 256, 0, stream>>>(trow, tcv, cur, epack);
    groupsort_kernel<<<NGRP, 256, 0, stream>>>(rp, epack);

    const int CELL_GRID = NN / 32;              // 3125
    const int SPMM_GRID = (NGRP + 3) / 4;       // 1563

    cell_kernel<true><<<CELL_GRID, 256, 0, stream>>>(xb, hb_b, Wib, Whb, bsum, cperm, hb_a);
    spmm_kernel<<<SPMM_GRID, 256, 0, stream>>>(rp, epack, hb_a, hb_b);
    for (int hop = 1; hop < HOPS; ++hop) {
        cell_kernel<false><<<CELL_GRID, 256, 0, stream>>>(xb, hb_b, Wib, Whb, bsum, cperm, hb_a);
        spmm_kernel<<<SPMM_GRID, 256, 0, stream>>>(rp, epack, hb_a, hb_b);
    }

    final_mfma_kernel<<<(NN + 63) / 64, 256, 0, stream>>>(hb_b, fcwb, fcb, out);
}

// Round 10
// 2896.858 us; speedup vs baseline: 3.4283x; 3.4283x over previous
//
#include <hip/hip_runtime.h>
#include <hip/hip_bf16.h>
#include <math.h>

constexpr int NN  = 100000;   // nodes
constexpr int EE  = 3200000;  // edges
constexpr int HID = 128;
constexpr int NG  = 512;      // 4*HID
constexpr int NOUT = 64;
constexpr int HOPS = 10;
constexpr int SCAN_BLK = 1024;
constexpr int NBLK_SCAN = (NN + SCAN_BLK - 1) / SCAN_BLK;   // 98

typedef __attribute__((ext_vector_type(8))) short short8;
typedef __attribute__((ext_vector_type(4))) float f32x4;
typedef unsigned long long ull;

__device__ __forceinline__ ushort f2bf(float f) {
    uint u = __builtin_bit_cast(uint, f);
    u += 0x7fff + ((u >> 16) & 1);          // RNE
    return (ushort)(u >> 16);
}
__device__ __forceinline__ float bflo(uint u) { return __builtin_bit_cast(float, u << 16); }
__device__ __forceinline__ float bfhi(uint u) { return __builtin_bit_cast(float, u & 0xffff0000u); }

__device__ __forceinline__ float sigf(float v) { return 1.0f / (1.0f + __expf(-v)); }
__device__ __forceinline__ float tanh_fast(float x) {
    float t = __expf(-2.0f * fabsf(x));
    float r = (1.0f - t) / (1.0f + t);
    return copysignf(r, x);
}

__device__ __forceinline__ short8 load_frag(const ushort* p) {
    return *reinterpret_cast<const short8*>(p);
}
__device__ __forceinline__ f32x4 mfma16(short8 a, short8 b, f32x4 c) {
    return __builtin_amdgcn_mfma_f32_16x16x32_bf16(a, b, c, 0, 0, 0);
}

// ---------------------------------------------------------------------------
// fp32 -> bf16 conversion (vectorized), n4 = n/4
// ---------------------------------------------------------------------------
__global__ __launch_bounds__(256) void convert_bf16_kernel(
    const float* __restrict__ src, ushort* __restrict__ dst, int n4)
{
    int i = blockIdx.x * 256 + threadIdx.x;
    if (i < n4) {
        float4 v = reinterpret_cast<const float4*>(src)[i];
        ushort4 o;
        o.x = f2bf(v.x); o.y = f2bf(v.y); o.z = f2bf(v.z); o.w = f2bf(v.w);
        reinterpret_cast<ushort4*>(dst)[i] = o;
    }
}

__global__ __launch_bounds__(256) void bsum_kernel(
    const float* __restrict__ bih, const float* __restrict__ bhh, float* __restrict__ bsum)
{
    int i = blockIdx.x * 256 + threadIdx.x;
    if (i < NG) bsum[i] = bih[i] + bhh[i];
}

// ---------------------------------------------------------------------------
// CSR build: histogram -> 3-stage scan -> packed scatter (simple; locality
// engineering of the scatter measured not-faster in rounds 6-9)
// ---------------------------------------------------------------------------
__global__ __launch_bounds__(256) void hist_kernel(const int* __restrict__ erow,
                                                   int* __restrict__ deg)
{
    int e = blockIdx.x * 256 + threadIdx.x;
    atomicAdd(&deg[erow[e]], 1);
}

__global__ __launch_bounds__(SCAN_BLK) void scan1_kernel(const int* __restrict__ deg,
                                                         int* __restrict__ bsums)
{
    __shared__ int tmp[SCAN_BLK];
    int t = threadIdx.x;
    int i = blockIdx.x * SCAN_BLK + t;
    tmp[t] = (i < NN) ? deg[i] : 0;
    __syncthreads();
    for (int off = SCAN_BLK / 2; off > 0; off >>= 1) {
        if (t < off) tmp[t] += tmp[t + off];
        __syncthreads();
    }
    if (t == 0) bsums[blockIdx.x] = tmp[0];
}

__global__ __launch_bounds__(128) void scan2_kernel(int* __restrict__ bsums)
{
    __shared__ int tmp[128];
    int t = threadIdx.x;
    tmp[t] = (t < NBLK_SCAN) ? bsums[t] : 0;
    __syncthreads();
    for (int off = 1; off < 128; off <<= 1) {
        int add = (t >= off) ? tmp[t - off] : 0;
        __syncthreads();
        tmp[t] += add;
        __syncthreads();
    }
    if (t < NBLK_SCAN) bsums[t] = (t == 0) ? 0 : tmp[t - 1];
}

__global__ __launch_bounds__(SCAN_BLK) void scan3_kernel(const int* __restrict__ deg,
                                                         const int* __restrict__ bsums,
                                                         int* __restrict__ rp,
                                                         int* __restrict__ cur)
{
    __shared__ int tmp[SCAN_BLK];
    int t = threadIdx.x;
    int i = blockIdx.x * SCAN_BLK + t;
    int v = (i < NN) ? deg[i] : 0;
    tmp[t] = v;
    __syncthreads();
    for (int off = 1; off < SCAN_BLK; off <<= 1) {
        int add = (t >= off) ? tmp[t - off] : 0;
        __syncthreads();
        tmp[t] += add;
        __syncthreads();
    }
    int incl = tmp[t] + bsums[blockIdx.x];
    if (i < NN) {
        rp[i + 1] = incl;
        cur[i] = incl - v;
    }
    if (i == 0) rp[0] = 0;
}

__global__ __launch_bounds__(256) void scatter_kernel(
    const int* __restrict__ erow, const int* __restrict__ ecol,
    const float* __restrict__ eval, int* __restrict__ cur,
    int2* __restrict__ epack)
{
    int e = blockIdx.x * 256 + threadIdx.x;
    int r = erow[e];
    int p = atomicAdd(&cur[r], 1);
    int2 pk;
    pk.x = ecol[e];
    pk.y = __builtin_bit_cast(int, eval[e]);
    epack[p] = pk;
}

// ---------------------------------------------------------------------------
// Fused LSTM cell, wave-specialized gates, two-pass K-loop (x-pass, h-pass).
// Block = 32 rows, 4 waves, 3 waves/SIMD.
// ---------------------------------------------------------------------------
template<bool FIRST>
__global__ __launch_bounds__(256, 3) void cell_kernel(
    const ushort* __restrict__ xb, const ushort* __restrict__ hb,
    const ushort* __restrict__ Wib, const ushort* __restrict__ Whb,
    const float* __restrict__ bsum, float* __restrict__ cperm,
    ushort* __restrict__ hout)
{
    __shared__ __align__(16) ushort lds_h[32 * 136];

    const int t  = threadIdx.x;
    const int l  = t & 63;
    const int w  = t >> 6;
    const int lr = l & 15;
    const int lk = l >> 4;
    const int row0 = blockIdx.x * 32;

    f32x4 acc[8][2];
#pragma unroll
    for (int nI = 0; nI < 8; ++nI) {
        float b = bsum[(4 * nI + w) * 16 + lr];
        acc[nI][0] = f32x4{b, b, b, b};
        acc[nI][1] = f32x4{b, b, b, b};
    }

    // ---- pass 1: x @ W_ih^T ----
    {
        short8 ax[2][4];
#pragma unroll
        for (int rf = 0; rf < 2; ++rf) {
            const size_t arow = (size_t)(row0 + rf * 16 + lr) * HID + lk * 8;
#pragma unroll
            for (int ks = 0; ks < 4; ++ks)
                ax[rf][ks] = load_frag(xb + arow + ks * 32);
        }
#pragma unroll
        for (int nI = 0; nI < 8; ++nI) {
            const int n = 4 * nI + w;
            const ushort* wip = Wib + (size_t)(n * 16 + lr) * HID + lk * 8;
            short8 bi[4];
#pragma unroll
            for (int ks = 0; ks < 4; ++ks) bi[ks] = load_frag(wip + ks * 32);
#pragma unroll
            for (int rf = 0; rf < 2; ++rf)
#pragma unroll
                for (int ks = 0; ks < 4; ++ks)
                    acc[nI][rf] = mfma16(ax[rf][ks], bi[ks], acc[nI][rf]);
        }
    }
    __builtin_amdgcn_sched_barrier(0);
    // ---- pass 2: h @ W_hh^T ----
    if (!FIRST) {
        short8 ah[2][4];
#pragma unroll
        for (int rf = 0; rf < 2; ++rf) {
            const size_t arow = (size_t)(row0 + rf * 16 + lr) * HID + lk * 8;
#pragma unroll
            for (int ks = 0; ks < 4; ++ks)
                ah[rf][ks] = load_frag(hb + arow + ks * 32);
        }
#pragma unroll
        for (int nI = 0; nI < 8; ++nI) {
            const int n = 4 * nI + w;
            const ushort* whp = Whb + (size_t)(n * 16 + lr) * HID + lk * 8;
            short8 bh[4];
#pragma unroll
            for (int ks = 0; ks < 4; ++ks) bh[ks] = load_frag(whp + ks * 32);
#pragma unroll
            for (int rf = 0; rf < 2; ++rf)
#pragma unroll
                for (int ks = 0; ks < 4; ++ks)
                    acc[nI][rf] = mfma16(ah[rf][ks], bh[ks], acc[nI][rf]);
        }
    }

    // epilogue: LSTM elementwise; c in permuted layout, h via LDS transpose
#pragma unroll
    for (int nj = 0; nj < 2; ++nj) {
        const int col = (w + 4 * nj) * 16 + lr;
#pragma unroll
        for (int rf = 0; rf < 2; ++rf) {
            f32x4 iv = acc[nj][rf];
            f32x4 fv = acc[nj + 2][rf];
            f32x4 gv = acc[nj + 4][rf];
            f32x4 ov = acc[nj + 6][rf];
            const size_t cidx = ((((size_t)blockIdx.x * 4 + w) * 2 + nj) * 2 + rf) * 64 + l;
            f32x4 cold;
            if (FIRST) cold = f32x4{0.f, 0.f, 0.f, 0.f};
            else       cold = reinterpret_cast<const f32x4*>(cperm)[cidx];
            f32x4 cn, hn;
#pragma unroll
            for (int jj = 0; jj < 4; ++jj) {
                float c2 = sigf(fv[jj]) * cold[jj] + sigf(iv[jj]) * tanh_fast(gv[jj]);
                cn[jj] = c2;
                hn[jj] = sigf(ov[jj]) * tanh_fast(c2);
            }
            reinterpret_cast<f32x4*>(cperm)[cidx] = cn;
            const int rbase = rf * 16 + lk * 4;
#pragma unroll
            for (int jj = 0; jj < 4; ++jj)
                lds_h[(rbase + jj) * 136 + col] = f2bf(hn[jj]);
        }
    }
    __syncthreads();
    {
        const ushort* lsrc = &lds_h[(t >> 3) * 136 + (t & 7) * 16];
        short8 v0 = *reinterpret_cast<const short8*>(lsrc);
        short8 v1 = *reinterpret_cast<const short8*>(lsrc + 8);
        ushort* gdst = hout + (size_t)row0 * HID + t * 16;
        *reinterpret_cast<short8*>(gdst) = v0;
        *reinterpret_cast<short8*>(gdst + 8) = v1;
    }
}

// ---------------------------------------------------------------------------
// SpMM: hout[r,:] = sum_e val[e] * hin[col[e],:]   (bf16 in/out, fp32 accum)
// One wave per row; 2 edges processed per wave step: lanes 0-31 take the even
// edge, lanes 32-63 the odd; each lane gathers uint2 (4 features, 8B).
// Unroll 4 -> 8 edge-gathers in flight per wave. __shfl_xor(32) merges halves.
// ---------------------------------------------------------------------------
__global__ __launch_bounds__(256) void spmm_kernel(
    const int* __restrict__ rp, const int2* __restrict__ epack,
    const ushort* __restrict__ hin, ushort* __restrict__ hout)
{
    const int r = blockIdx.x * 4 + (threadIdx.x >> 6);
    if (r >= NN) return;
    const int l = threadIdx.x & 63;
    const int half = l >> 5;                 // which edge of a pair
    const int fl = l & 31;                   // feature quad: feats 4*fl..4*fl+3
    const ushort* hbase = hin + fl * 4;
    const int beg = rp[r], end = rp[r + 1];
    const ull* eq = reinterpret_cast<const ull*>(epack);

    float a0 = 0.f, a1 = 0.f, a2 = 0.f, a3 = 0.f;
    float b0 = 0.f, b1 = 0.f, b2 = 0.f, b3 = 0.f;
    float c0 = 0.f, c1 = 0.f, c2 = 0.f, c3 = 0.f;
    float d0 = 0.f, d1 = 0.f, d2 = 0.f, d3 = 0.f;

    int e = beg;
    for (; e + 8 <= end; e += 8) {
        ull u0 = __builtin_nontemporal_load(eq + e + 0 + half);
        ull u1 = __builtin_nontemporal_load(eq + e + 2 + half);
        ull u2 = __builtin_nontemporal_load(eq + e + 4 + half);
        ull u3 = __builtin_nontemporal_load(eq + e + 6 + half);
        uint2 g0 = *reinterpret_cast<const uint2*>(hbase + (size_t)(uint)u0 * HID);
        uint2 g1 = *reinterpret_cast<const uint2*>(hbase + (size_t)(uint)u1 * HID);
        uint2 g2 = *reinterpret_cast<const uint2*>(hbase + (size_t)(uint)u2 * HID);
        uint2 g3 = *reinterpret_cast<const uint2*>(hbase + (size_t)(uint)u3 * HID);
        float v0 = __builtin_bit_cast(float, (uint)(u0 >> 32));
        float v1 = __builtin_bit_cast(float, (uint)(u1 >> 32));
        float v2 = __builtin_bit_cast(float, (uint)(u2 >> 32));
        float v3 = __builtin_bit_cast(float, (uint)(u3 >> 32));
        a0 += v0 * bflo(g0.x); a1 += v0 * bfhi(g0.x); a2 += v0 * bflo(g0.y); a3 += v0 * bfhi(g0.y);
        b0 += v1 * bflo(g1.x); b1 += v1 * bfhi(g1.x); b2 += v1 * bflo(g1.y); b3 += v1 * bfhi(g1.y);
        c0 += v2 * bflo(g2.x); c1 += v2 * bfhi(g2.x); c2 += v2 * bflo(g2.y); c3 += v2 * bfhi(g2.y);
        d0 += v3 * bflo(g3.x); d1 += v3 * bfhi(g3.x); d2 += v3 * bflo(g3.y); d3 += v3 * bfhi(g3.y);
    }
    for (; e < end; e += 2) {
        int idx = e + half;
        if (idx < end) {
            ull u0 = __builtin_nontemporal_load(eq + idx);
            uint2 g0 = *reinterpret_cast<const uint2*>(hbase + (size_t)(uint)u0 * HID);
            float v0 = __builtin_bit_cast(float, (uint)(u0 >> 32));
            a0 += v0 * bflo(g0.x); a1 += v0 * bfhi(g0.x);
            a2 += v0 * bflo(g0.y); a3 += v0 * bfhi(g0.y);
        }
    }
    float s0 = (a0 + b0) + (c0 + d0);
    float s1 = (a1 + b1) + (c1 + d1);
    float s2 = (a2 + b2) + (c2 + d2);
    float s3 = (a3 + b3) + (c3 + d3);
    s0 += __shfl_xor(s0, 32);
    s1 += __shfl_xor(s1, 32);
    s2 += __shfl_xor(s2, 32);
    s3 += __shfl_xor(s3, 32);
    if (half == 0) {
        uint2 o;
        o.x = ((uint)f2bf(s1) << 16) | (uint)f2bf(s0);
        o.y = ((uint)f2bf(s3) << 16) | (uint)f2bf(s2);
        *reinterpret_cast<uint2*>(hout + (size_t)r * HID + fl * 4) = o;
    }
}

// ---------------------------------------------------------------------------
// final: out = relu(h) @ fc_w^T + fc_b  (MFMA)
// ---------------------------------------------------------------------------
__global__ __launch_bounds__(256) void final_mfma_kernel(
    const ushort* __restrict__ hb, const ushort* __restrict__ fcwb,
    const float* __restrict__ fcb, float* __restrict__ out)
{
    const int t = threadIdx.x;
    const int l = t & 63;
    const int w = t >> 6;
    const int lr = l & 15;
    const int lk = l >> 4;
    const int row0 = blockIdx.x * 64 + w * 16;

    f32x4 acc[4];
#pragma unroll
    for (int n = 0; n < 4; ++n) {
        float b = fcb[n * 16 + lr];
        acc[n] = f32x4{b, b, b, b};
    }

    const short8 z8 = {0, 0, 0, 0, 0, 0, 0, 0};
    const int arow = row0 + lr;
    const bool aok = arow < NN;
    short8 a[4];
#pragma unroll
    for (int ks = 0; ks < 4; ++ks) {
        short8 v = aok ? load_frag(hb + (size_t)arow * HID + ks * 32 + lk * 8) : z8;
#pragma unroll
        for (int i = 0; i < 8; ++i) {
            ushort u = (ushort)v[i];
            if (u & 0x8000) v[i] = 0;   // relu in bf16
        }
        a[ks] = v;
    }

#pragma unroll
    for (int n = 0; n < 4; ++n) {
        const ushort* wp = fcwb + (size_t)(n * 16 + lr) * HID + lk * 8;
#pragma unroll
        for (int ks = 0; ks < 4; ++ks)
            acc[n] = mfma16(a[ks], load_frag(wp + ks * 32), acc[n]);
    }

#pragma unroll
    for (int n = 0; n < 4; ++n) {
#pragma unroll
        for (int j = 0; j < 4; ++j) {
            int row = row0 + lk * 4 + j;
            if (row < NN) out[(size_t)row * NOUT + n * 16 + lr] = acc[n][j];
        }
    }
}

// ---------------------------------------------------------------------------
extern "C" void kernel_launch(void* const* d_in, const int* in_sizes, int n_in,
                              void* d_out, int out_size, void* d_ws, size_t ws_size,
                              hipStream_t stream)
{
    const float* x    = (const float*)d_in[0];
    const int*   erow = (const int*)d_in[1];
    const int*   ecol = (const int*)d_in[2];
    const float* eval = (const float*)d_in[3];
    const float* Wih  = (const float*)d_in[4];
    const float* Whh  = (const float*)d_in[5];
    const float* bih  = (const float*)d_in[6];
    const float* bhh  = (const float*)d_in[7];
    const float* fcw  = (const float*)d_in[8];
    const float* fcb  = (const float*)d_in[9];
    float* out = (float*)d_out;

    char* ws = (char*)d_ws;
    size_t off = 0;
    auto alloc = [&](size_t bytes) -> void* {
        void* p = ws + off;
        off = (off + bytes + 255) & ~(size_t)255;
        return p;
    };
    ushort* hb_a  = (ushort*)alloc((size_t)NN * HID * 2);
    ushort* hb_b  = (ushort*)alloc((size_t)NN * HID * 2);
    float*  cperm = (float*)alloc((size_t)NN * HID * 4);
    ushort* xb    = (ushort*)alloc((size_t)NN * HID * 2);
    ushort* Wib   = (ushort*)alloc((size_t)NG * HID * 2);
    ushort* Whb   = (ushort*)alloc((size_t)NG * HID * 2);
    ushort* fcwb  = (ushort*)alloc((size_t)NOUT * HID * 2);
    float*  bsum  = (float*)alloc((size_t)NG * 4);
    int*    rp    = (int*)alloc((size_t)(NN + 1) * 4);
    int*    deg   = (int*)alloc((size_t)NN * 4);
    int*    cur   = (int*)alloc((size_t)NN * 4);
    int*    bsums = (int*)alloc((size_t)NBLK_SCAN * 4);
    int2*   epack = (int2*)alloc((size_t)EE * 8);
    (void)ws_size;

    // conversions to bf16
    convert_bf16_kernel<<<(NN * HID / 4 + 255) / 256, 256, 0, stream>>>(x, xb, NN * HID / 4);
    convert_bf16_kernel<<<(NG * HID / 4 + 255) / 256, 256, 0, stream>>>(Wih, Wib, NG * HID / 4);
    convert_bf16_kernel<<<(NG * HID / 4 + 255) / 256, 256, 0, stream>>>(Whh, Whb, NG * HID / 4);
    convert_bf16_kernel<<<(NOUT * HID / 4 + 255) / 256, 256, 0, stream>>>(fcw, fcwb, NOUT * HID / 4);
    bsum_kernel<<<2, 256, 0, stream>>>(bih, bhh, bsum);

    // CSR build
    hipMemsetAsync(deg, 0, (size_t)NN * 4, stream);
    hist_kernel<<<EE / 256, 256, 0, stream>>>(erow, deg);
    scan1_kernel<<<NBLK_SCAN, SCAN_BLK, 0, stream>>>(deg, bsums);
    scan2_kernel<<<1, 128, 0, stream>>>(bsums);
    scan3_kernel<<<NBLK_SCAN, SCAN_BLK, 0, stream>>>(deg, bsums, rp, cur);
    scatter_kernel<<<EE / 256, 256, 0, stream>>>(erow, ecol, eval, cur, epack);

    const int CELL_GRID = NN / 32;         // 3125
    const int SPMM_GRID = NN / 4;          // 25000

    cell_kernel<true><<<CELL_GRID, 256, 0, stream>>>(xb, hb_b, Wib, Whb, bsum, cperm, hb_a);
    spmm_kernel<<<SPMM_GRID, 256, 0, stream>>>(rp, epack, hb_a, hb_b);
    for (int hop = 1; hop < HOPS; ++hop) {
        cell_kernel<false><<<CELL_GRID, 256, 0, stream>>>(xb, hb_b, Wib, Whb, bsum, cperm, hb_a);
        spmm_kernel<<<SPMM_GRID, 256, 0, stream>>>(rp, epack, hb_a, hb_b);
    }

    final_mfma_kernel<<<(NN + 63) / 64, 256, 0, stream>>>(hb_b, fcwb, fcb, out);
}